// Round 2
// baseline (2005.340 us; speedup 1.0000x reference)
//
#include <hip/hip_runtime.h>

#define B_ 2
#define N_ 20000
#define C_ 256
#define K_ 16
#define H_ 128
#define ROWS (B_ * N_)  // 40000

__device__ __forceinline__ float wred(float v) {
#pragma unroll
    for (int off = 32; off > 0; off >>= 1) v += __shfl_xor(v, off, 64);
    return v;
}

// ---------------- gate: alpha = softmax(relu(x3@Wg1^T+bg1)@Wg2^T+bg2) -------
extern "C" __global__ void __launch_bounds__(256)
gate_kernel(const float* __restrict__ x3, const float* __restrict__ Wg1,
            const float* __restrict__ bg1, const float* __restrict__ Wg2,
            const float* __restrict__ bg2, float* __restrict__ alpha) {
    __shared__ float xs[4][C_];
    const int tid = threadIdx.x;
    const int w = tid >> 6, lane = tid & 63;
    const int row = blockIdx.x * 4 + w;
    {
        float4 v = *(const float4*)(x3 + (size_t)row * C_ + lane * 4);
        *(float4*)&xs[w][lane * 4] = v;
    }
    __syncthreads();
    float h0 = bg1[lane];
    float h1 = bg1[lane + 64];
    const float* w1a = Wg1 + (size_t)lane * C_;
    const float* w1b = Wg1 + (size_t)(lane + 64) * C_;
#pragma unroll 8
    for (int c = 0; c < C_; c += 4) {
        float4 wa = *(const float4*)(w1a + c);
        float4 wb = *(const float4*)(w1b + c);
        float x0 = xs[w][c], x1 = xs[w][c + 1], x2 = xs[w][c + 2], x3v = xs[w][c + 3];
        h0 += x0 * wa.x + x1 * wa.y + x2 * wa.z + x3v * wa.w;
        h1 += x0 * wb.x + x1 * wb.y + x2 * wb.z + x3v * wb.w;
    }
    h0 = fmaxf(h0, 0.f);
    h1 = fmaxf(h1, 0.f);
    float lg[3];
#pragma unroll
    for (int l = 0; l < 3; ++l) {
        const float* w2 = Wg2 + l * H_;
        float p = h0 * w2[lane] + h1 * w2[lane + 64];
        lg[l] = wred(p) + bg2[l];
    }
    float m = fmaxf(lg[0], fmaxf(lg[1], lg[2]));
    float e0 = expf(lg[0] - m), e1 = expf(lg[1] - m), e2 = expf(lg[2] - m);
    float inv = 1.f / (e0 + e1 + e2);
    if (lane == 0) {
        alpha[row * 3 + 0] = e0 * inv;
        alpha[row * 3 + 1] = e1 * inv;
        alpha[row * 3 + 2] = e2 * inv;
    }
}

// ---------------- fused Q/K/V GEMM: O = A @ W^T + b (fp32) ------------------
#define BM 64
#define BN 64
#define BK 16
#define LDA 68

extern "C" __global__ void __launch_bounds__(256)
gemm_qkv(const float* __restrict__ Aq, const float* __restrict__ A3,
         const float* __restrict__ Wq, const float* __restrict__ Wk,
         const float* __restrict__ Wv, const float* __restrict__ bq,
         const float* __restrict__ bk, const float* __restrict__ bv,
         float* __restrict__ Oq, float* __restrict__ Ok, float* __restrict__ Ov) {
    const int z = blockIdx.z;
    const float* A = (z == 0) ? Aq : A3;
    const float* W = (z == 0) ? Wq : (z == 1 ? Wk : Wv);
    const float* bias = (z == 0) ? bq : (z == 1 ? bk : bv);
    float* O = (z == 0) ? Oq : (z == 1 ? Ok : Ov);

    const int m0 = blockIdx.x * BM;
    const int n0 = blockIdx.y * BN;
    const int tid = threadIdx.x;
    const int tx = tid & 15, ty = tid >> 4;
    const int lr = tid >> 2;
    const int lc = (tid & 3) * 4;

    __shared__ float As[BK][LDA];
    __shared__ float Bs[BK][LDA];

    float acc[4][4] = {};

    for (int k0 = 0; k0 < C_; k0 += BK) {
        float4 av = *(const float4*)(A + (size_t)(m0 + lr) * C_ + k0 + lc);
        float4 wv = *(const float4*)(W + (size_t)(n0 + lr) * C_ + k0 + lc);
        As[lc + 0][lr] = av.x;
        As[lc + 1][lr] = av.y;
        As[lc + 2][lr] = av.z;
        As[lc + 3][lr] = av.w;
        Bs[lc + 0][lr] = wv.x;
        Bs[lc + 1][lr] = wv.y;
        Bs[lc + 2][lr] = wv.z;
        Bs[lc + 3][lr] = wv.w;
        __syncthreads();
#pragma unroll
        for (int kk = 0; kk < BK; ++kk) {
            float ra[4], rb[4];
#pragma unroll
            for (int i = 0; i < 4; ++i) ra[i] = As[kk][ty * 4 + i];
#pragma unroll
            for (int j = 0; j < 4; ++j) rb[j] = Bs[kk][tx * 4 + j];
#pragma unroll
            for (int i = 0; i < 4; ++i)
#pragma unroll
                for (int j = 0; j < 4; ++j) acc[i][j] += ra[i] * rb[j];
        }
        __syncthreads();
    }

    float bv4[4];
#pragma unroll
    for (int j = 0; j < 4; ++j) bv4[j] = bias[n0 + tx * 4 + j];
#pragma unroll
    for (int i = 0; i < 4; ++i) {
        float4 o;
        o.x = acc[i][0] + bv4[0];
        o.y = acc[i][1] + bv4[1];
        o.z = acc[i][2] + bv4[2];
        o.w = acc[i][3] + bv4[3];
        *(float4*)&O[(size_t)(m0 + ty * 4 + i) * C_ + n0 + tx * 4] = o;
    }
}

// ---------------- attention + LN + alpha-weighted accumulate into out -------
extern "C" __global__ void __launch_bounds__(256)
attn_kernel(const float* __restrict__ q, const float* __restrict__ kf,
            const float* __restrict__ vf, const int* __restrict__ knn,
            const float* __restrict__ alpha, const float* __restrict__ lng,
            const float* __restrict__ lnb, float* __restrict__ accum, const int iblk) {
    const int tid = threadIdx.x;
    const int w = tid >> 6, lane = tid & 63;
    const int row = blockIdx.x * 4 + w;
    const int b = row / N_;
    const int n = row - b * N_;
    const int c0 = lane * 4;

    float4 q4 = *(const float4*)(q + (size_t)row * C_ + c0);
    float s[K_];
    float4 vk[K_];
#pragma unroll
    for (int k = 0; k < K_; ++k) {
        const int idx = knn[n * K_ + k];
        const size_t base = ((size_t)b * N_ + idx) * C_ + c0;
        float4 k4 = *(const float4*)(kf + base);
        vk[k] = *(const float4*)(vf + base);
        s[k] = wred(q4.x * k4.x + q4.y * k4.y + q4.z * k4.z + q4.w * k4.w) * 0.0625f;
    }
    float m = s[0];
#pragma unroll
    for (int k = 1; k < K_; ++k) m = fmaxf(m, s[k]);
    float sum = 0.f;
#pragma unroll
    for (int k = 0; k < K_; ++k) {
        s[k] = expf(s[k] - m);
        sum += s[k];
    }
    const float inv = 1.f / sum;
    float4 o = make_float4(0.f, 0.f, 0.f, 0.f);
#pragma unroll
    for (int k = 0; k < K_; ++k) {
        const float a = s[k] * inv;
        o.x += a * vk[k].x;
        o.y += a * vk[k].y;
        o.z += a * vk[k].z;
        o.w += a * vk[k].w;
    }
    float4 r = make_float4(o.x + q4.x, o.y + q4.y, o.z + q4.z, o.w + q4.w);
    float s1 = wred(r.x + r.y + r.z + r.w);
    float s2 = wred(r.x * r.x + r.y * r.y + r.z * r.z + r.w * r.w);
    const float mean = s1 * (1.f / C_);
    const float var = s2 * (1.f / C_) - mean * mean;
    const float rstd = rsqrtf(var + 1e-5f);
    const float* g = lng + iblk * C_ + c0;
    const float* bb = lnb + iblk * C_ + c0;
    float4 y;
    y.x = (r.x - mean) * rstd * g[0] + bb[0];
    y.y = (r.y - mean) * rstd * g[1] + bb[1];
    y.z = (r.z - mean) * rstd * g[2] + bb[2];
    y.w = (r.w - mean) * rstd * g[3] + bb[3];
    const float a = alpha[row * 3 + iblk];
    float* ap = accum + (size_t)row * C_ + c0;
    if (iblk == 0) {
        *(float4*)ap = make_float4(a * y.x, a * y.y, a * y.z, a * y.w);
    } else {
        float4 p = *(const float4*)ap;
        p.x += a * y.x;
        p.y += a * y.y;
        p.z += a * y.z;
        p.w += a * y.w;
        *(float4*)ap = p;
    }
}

// ---------------- final LN(accum + x3), in-place on out ---------------------
extern "C" __global__ void __launch_bounds__(256)
final_kernel(float* __restrict__ accum, const float* __restrict__ x3,
             const float* __restrict__ fng, const float* __restrict__ fnb) {
    const int tid = threadIdx.x;
    const int w = tid >> 6, lane = tid & 63;
    const int row = blockIdx.x * 4 + w;
    const int c0 = lane * 4;
    float4 a = *(const float4*)(accum + (size_t)row * C_ + c0);
    float4 xv = *(const float4*)(x3 + (size_t)row * C_ + c0);
    float4 r = make_float4(a.x + xv.x, a.y + xv.y, a.z + xv.z, a.w + xv.w);
    float s1 = wred(r.x + r.y + r.z + r.w);
    float s2 = wred(r.x * r.x + r.y * r.y + r.z * r.z + r.w * r.w);
    const float mean = s1 * (1.f / C_);
    const float var = s2 * (1.f / C_) - mean * mean;
    const float rstd = rsqrtf(var + 1e-5f);
    const float* g = fng + c0;
    const float* bb = fnb + c0;
    float4 y;
    y.x = (r.x - mean) * rstd * g[0] + bb[0];
    y.y = (r.y - mean) * rstd * g[1] + bb[1];
    y.z = (r.z - mean) * rstd * g[2] + bb[2];
    y.w = (r.w - mean) * rstd * g[3] + bb[3];
    *(float4*)(accum + (size_t)row * C_ + c0) = y;
}

extern "C" void kernel_launch(void* const* d_in, const int* in_sizes, int n_in,
                              void* d_out, int out_size, void* d_ws, size_t ws_size,
                              hipStream_t stream) {
    const float* x0 = (const float*)d_in[0];
    const float* x1 = (const float*)d_in[1];
    const float* x2 = (const float*)d_in[2];
    const float* x3 = (const float*)d_in[3];
    const int* knn = (const int*)d_in[4];
    const float* Wq = (const float*)d_in[5];
    const float* bq = (const float*)d_in[6];
    const float* Wk = (const float*)d_in[7];
    const float* bk = (const float*)d_in[8];
    const float* Wv = (const float*)d_in[9];
    const float* bv = (const float*)d_in[10];
    const float* ln_g = (const float*)d_in[11];
    const float* ln_b = (const float*)d_in[12];
    const float* Wg1 = (const float*)d_in[13];
    const float* bg1 = (const float*)d_in[14];
    const float* Wg2 = (const float*)d_in[15];
    const float* bg2 = (const float*)d_in[16];
    const float* fn_g = (const float*)d_in[17];
    const float* fn_b = (const float*)d_in[18];
    float* out = (float*)d_out;

    float* ws = (float*)d_ws;
    const size_t BNC = (size_t)ROWS * C_;  // 10,240,000
    float* qb = ws;
    float* kb = ws + BNC;
    float* vb = ws + 2 * BNC;
    float* alpha = ws + 3 * BNC;

    gate_kernel<<<ROWS / 4, 256, 0, stream>>>(x3, Wg1, bg1, Wg2, bg2, alpha);

    const float* xq[3] = {x0, x1, x2};
    for (int i = 0; i < 3; ++i) {
        gemm_qkv<<<dim3(ROWS / BM, C_ / BN, 3), 256, 0, stream>>>(
            xq[i], x3, Wq + (size_t)i * C_ * C_, Wk + (size_t)i * C_ * C_,
            Wv + (size_t)i * C_ * C_, bq + i * C_, bk + i * C_, bv + i * C_,
            qb, kb, vb);
        attn_kernel<<<ROWS / 4, 256, 0, stream>>>(qb, kb, vb, knn, alpha, ln_g,
                                                  ln_b, out, i);
    }
    final_kernel<<<ROWS / 4, 256, 0, stream>>>(out, x3, fn_g, fn_b);
}

// Round 3
// 685.777 us; speedup vs baseline: 2.9242x; 2.9242x over previous
//
#include <hip/hip_runtime.h>

#define B_ 2
#define N_ 20000
#define C_ 256
#define K_ 16
#define H_ 128
#define ROWS (B_ * N_)       // 40000
#define MT 313               // ceil(40000/128)
#define MPAD (MT * 128)      // 40064

typedef __attribute__((ext_vector_type(8))) short bf16x8;
typedef __attribute__((ext_vector_type(4))) float f32x4;

__device__ __forceinline__ float us2f(unsigned short u) {
    return __uint_as_float(((unsigned int)u) << 16);
}
__device__ __forceinline__ unsigned short f2us(float f) {
    unsigned int u = __float_as_uint(f);
    unsigned int r = (u + 0x7fffu + ((u >> 16) & 1u)) >> 16;
    return (unsigned short)r;
}
__device__ __forceinline__ float wred(float v) {
#pragma unroll
    for (int off = 32; off > 0; off >>= 1) v += __shfl_xor(v, off, 64);
    return v;
}
__device__ __forceinline__ void gld_lds16(const unsigned short* g, unsigned short* l) {
    __builtin_amdgcn_global_load_lds(
        (__attribute__((address_space(1))) void*)(g),
        (__attribute__((address_space(3))) void*)(l), 16, 0, 0);
}

// ---------------- fp32 -> bf16 convert ---------------------------------------
extern "C" __global__ void __launch_bounds__(256)
cvt_kernel(const float* __restrict__ src, unsigned short* __restrict__ dst, int n4) {
    int t = blockIdx.x * 256 + threadIdx.x;
    if (t >= n4) return;
    float4 v = ((const float4*)src)[t];
    ushort4 o;
    o.x = f2us(v.x); o.y = f2us(v.y); o.z = f2us(v.z); o.w = f2us(v.w);
    ((ushort4*)dst)[t] = o;
}

// ---------------- bf16 MFMA GEMM: O = A @ W^T + b, O in bf16 -----------------
// A: MPAD x 256 bf16 row-major.  W: N x 256 bf16 row-major.  bias: fp32.
// grid: (MT, N/128, nz).  z picks (A, W, bias, O) triple.
extern "C" __global__ void __launch_bounds__(256)
gemm_bf16(const unsigned short* __restrict__ A0, const unsigned short* __restrict__ A12,
          const unsigned short* __restrict__ W0, const unsigned short* __restrict__ W1,
          const unsigned short* __restrict__ W2, const float* __restrict__ b0,
          const float* __restrict__ b1, const float* __restrict__ b2,
          unsigned short* __restrict__ O0, unsigned short* __restrict__ O1,
          unsigned short* __restrict__ O2, const int Mvalid, const int ldo) {
    const int z = blockIdx.z;
    const unsigned short* A = (z == 0) ? A0 : A12;
    const unsigned short* W = (z == 0) ? W0 : (z == 1 ? W1 : W2);
    const float* bias = (z == 0) ? b0 : (z == 1 ? b1 : b2);
    unsigned short* O = (z == 0) ? O0 : (z == 1 ? O1 : O2);

    const int m0 = blockIdx.x * 128;
    const int n0 = blockIdx.y * 128;
    const int tid = threadIdx.x;
    const int w = tid >> 6, lane = tid & 63;
    const int l15 = lane & 15, l4 = lane >> 4;
    const int rowq = (w >> 1) * 64;   // wave quadrant
    const int colq = (w & 1) * 64;

    __shared__ unsigned short As[128 * 32];
    __shared__ unsigned short Bs[128 * 32];

    f32x4 acc[4][4] = {};

    const int srow = w * 16 + (lane >> 2);   // staging row within 64-row group
    const int schunk = (lane & 3) * 8;       // 8 bf16 = 16 B

    for (int k0 = 0; k0 < 256; k0 += 32) {
        __syncthreads();
#pragma unroll
        for (int issue = 0; issue < 2; ++issue) {
            const int ra = m0 + issue * 64 + srow;
            const int rb = n0 + issue * 64 + srow;
            gld_lds16(A + (size_t)ra * 256 + k0 + schunk, As + issue * 2048 + w * 512);
            gld_lds16(W + (size_t)rb * 256 + k0 + schunk, Bs + issue * 2048 + w * 512);
        }
        __syncthreads();
        bf16x8 a[4], b[4];
#pragma unroll
        for (int i = 0; i < 4; ++i)
            a[i] = *(const bf16x8*)&As[(rowq + i * 16 + l15) * 32 + l4 * 8];
#pragma unroll
        for (int j = 0; j < 4; ++j)
            b[j] = *(const bf16x8*)&Bs[(colq + j * 16 + l15) * 32 + l4 * 8];
#pragma unroll
        for (int i = 0; i < 4; ++i)
#pragma unroll
            for (int j = 0; j < 4; ++j)
                acc[i][j] = __builtin_amdgcn_mfma_f32_16x16x32_bf16(a[i], b[j], acc[i][j], 0, 0, 0);
    }

#pragma unroll
    for (int j = 0; j < 4; ++j) {
        const int gcol = n0 + colq + j * 16 + l15;
        const float bj = bias[gcol];
#pragma unroll
        for (int i = 0; i < 4; ++i) {
#pragma unroll
            for (int r = 0; r < 4; ++r) {
                const int grow = m0 + rowq + i * 16 + l4 * 4 + r;
                if (grow < Mvalid) O[(size_t)grow * ldo + gcol] = f2us(acc[i][j][r] + bj);
            }
        }
    }
}

// ---------------- gate stage 2: alpha = softmax(relu(H)@Wg2^T + bg2) ---------
extern "C" __global__ void __launch_bounds__(256)
gate2_kernel(const unsigned short* __restrict__ Hbf, const float* __restrict__ Wg2,
             const float* __restrict__ bg2, float* __restrict__ alpha) {
    const int tid = threadIdx.x;
    const int w = tid >> 6, lane = tid & 63;
    const int row = blockIdx.x * 4 + w;
    const float h0 = fmaxf(us2f(Hbf[(size_t)row * H_ + lane]), 0.f);
    const float h1 = fmaxf(us2f(Hbf[(size_t)row * H_ + 64 + lane]), 0.f);
    float lg[3];
#pragma unroll
    for (int l = 0; l < 3; ++l) {
        const float* w2 = Wg2 + l * H_;
        lg[l] = wred(h0 * w2[lane] + h1 * w2[lane + 64]) + bg2[l];
    }
    float m = fmaxf(lg[0], fmaxf(lg[1], lg[2]));
    float e0 = expf(lg[0] - m), e1 = expf(lg[1] - m), e2 = expf(lg[2] - m);
    float inv = 1.f / (e0 + e1 + e2);
    if (lane == 0) {
        alpha[row * 3 + 0] = e0 * inv;
        alpha[row * 3 + 1] = e1 * inv;
        alpha[row * 3 + 2] = e2 * inv;
    }
}

// ---------------- attention + LN + alpha-weighted accumulate into out --------
extern "C" __global__ void __launch_bounds__(256)
attn_kernel(const unsigned short* __restrict__ q, const unsigned short* __restrict__ kf,
            const unsigned short* __restrict__ vf, const int* __restrict__ knn,
            const float* __restrict__ alpha, const float* __restrict__ lng,
            const float* __restrict__ lnb, float* __restrict__ accum, const int iblk) {
    const int tid = threadIdx.x;
    const int w = tid >> 6, lane = tid & 63;
    const int row = blockIdx.x * 4 + w;
    const int b = row / N_;
    const int n = row - b * N_;
    const int c0 = lane * 4;

    ushort4 qu = *(const ushort4*)(q + (size_t)row * C_ + c0);
    float4 q4 = make_float4(us2f(qu.x), us2f(qu.y), us2f(qu.z), us2f(qu.w));
    float s[K_];
    float4 vk[K_];
#pragma unroll
    for (int k = 0; k < K_; ++k) {
        const int idx = knn[n * K_ + k];
        const size_t base = ((size_t)b * N_ + idx) * C_ + c0;
        ushort4 ku = *(const ushort4*)(kf + base);
        ushort4 vu = *(const ushort4*)(vf + base);
        vk[k] = make_float4(us2f(vu.x), us2f(vu.y), us2f(vu.z), us2f(vu.w));
        s[k] = wred(q4.x * us2f(ku.x) + q4.y * us2f(ku.y) + q4.z * us2f(ku.z) +
                    q4.w * us2f(ku.w)) * 0.0625f;
    }
    float m = s[0];
#pragma unroll
    for (int k = 1; k < K_; ++k) m = fmaxf(m, s[k]);
    float sum = 0.f;
#pragma unroll
    for (int k = 0; k < K_; ++k) {
        s[k] = expf(s[k] - m);
        sum += s[k];
    }
    const float inv = 1.f / sum;
    float4 o = make_float4(0.f, 0.f, 0.f, 0.f);
#pragma unroll
    for (int k = 0; k < K_; ++k) {
        const float a = s[k] * inv;
        o.x += a * vk[k].x;
        o.y += a * vk[k].y;
        o.z += a * vk[k].z;
        o.w += a * vk[k].w;
    }
    float4 r = make_float4(o.x + q4.x, o.y + q4.y, o.z + q4.z, o.w + q4.w);
    float s1 = wred(r.x + r.y + r.z + r.w);
    float s2 = wred(r.x * r.x + r.y * r.y + r.z * r.z + r.w * r.w);
    const float mean = s1 * (1.f / C_);
    const float var = s2 * (1.f / C_) - mean * mean;
    const float rstd = rsqrtf(var + 1e-5f);
    const float* g = lng + iblk * C_ + c0;
    const float* bb = lnb + iblk * C_ + c0;
    float4 y;
    y.x = (r.x - mean) * rstd * g[0] + bb[0];
    y.y = (r.y - mean) * rstd * g[1] + bb[1];
    y.z = (r.z - mean) * rstd * g[2] + bb[2];
    y.w = (r.w - mean) * rstd * g[3] + bb[3];
    const float a = alpha[row * 3 + iblk];
    float* ap = accum + (size_t)row * C_ + c0;
    if (iblk == 0) {
        *(float4*)ap = make_float4(a * y.x, a * y.y, a * y.z, a * y.w);
    } else {
        float4 p = *(const float4*)ap;
        p.x += a * y.x;
        p.y += a * y.y;
        p.z += a * y.z;
        p.w += a * y.w;
        *(float4*)ap = p;
    }
}

// ---------------- final LN(accum + x3), in-place on out ----------------------
extern "C" __global__ void __launch_bounds__(256)
final_kernel(float* __restrict__ accum, const float* __restrict__ x3,
             const float* __restrict__ fng, const float* __restrict__ fnb) {
    const int tid = threadIdx.x;
    const int w = tid >> 6, lane = tid & 63;
    const int row = blockIdx.x * 4 + w;
    const int c0 = lane * 4;
    float4 a = *(const float4*)(accum + (size_t)row * C_ + c0);
    float4 xv = *(const float4*)(x3 + (size_t)row * C_ + c0);
    float4 r = make_float4(a.x + xv.x, a.y + xv.y, a.z + xv.z, a.w + xv.w);
    float s1 = wred(r.x + r.y + r.z + r.w);
    float s2 = wred(r.x * r.x + r.y * r.y + r.z * r.z + r.w * r.w);
    const float mean = s1 * (1.f / C_);
    const float var = s2 * (1.f / C_) - mean * mean;
    const float rstd = rsqrtf(var + 1e-5f);
    const float* g = fng + c0;
    const float* bb = fnb + c0;
    float4 y;
    y.x = (r.x - mean) * rstd * g[0] + bb[0];
    y.y = (r.y - mean) * rstd * g[1] + bb[1];
    y.z = (r.z - mean) * rstd * g[2] + bb[2];
    y.w = (r.w - mean) * rstd * g[3] + bb[3];
    *(float4*)(accum + (size_t)row * C_ + c0) = y;
}

extern "C" void kernel_launch(void* const* d_in, const int* in_sizes, int n_in,
                              void* d_out, int out_size, void* d_ws, size_t ws_size,
                              hipStream_t stream) {
    const float* x0 = (const float*)d_in[0];
    const float* x1 = (const float*)d_in[1];
    const float* x2 = (const float*)d_in[2];
    const float* x3 = (const float*)d_in[3];
    const int* knn = (const int*)d_in[4];
    const float* Wq = (const float*)d_in[5];
    const float* bq = (const float*)d_in[6];
    const float* Wk = (const float*)d_in[7];
    const float* bk = (const float*)d_in[8];
    const float* Wv = (const float*)d_in[9];
    const float* bv = (const float*)d_in[10];
    const float* ln_g = (const float*)d_in[11];
    const float* ln_b = (const float*)d_in[12];
    const float* Wg1 = (const float*)d_in[13];
    const float* bg1 = (const float*)d_in[14];
    const float* Wg2 = (const float*)d_in[15];
    const float* bg2 = (const float*)d_in[16];
    const float* fn_g = (const float*)d_in[17];
    const float* fn_b = (const float*)d_in[18];
    float* out = (float*)d_out;

    unsigned char* w8 = (unsigned char*)d_ws;
    const size_t XBF = (size_t)MPAD * C_ * 2;        // 20,512,768 B
    const size_t HBF = (size_t)MPAD * H_ * 2;        // 10,256,384 B
    const size_t WBLOB = (size_t)3 * C_ * C_ * 2;    //    393,216 B
    unsigned short* x3bf = (unsigned short*)(w8);
    unsigned short* xqbf = (unsigned short*)(w8 + XBF);
    unsigned short* qbf  = (unsigned short*)(w8 + 2 * XBF);
    unsigned short* kbf  = (unsigned short*)(w8 + 3 * XBF);
    unsigned short* vbf  = (unsigned short*)(w8 + 4 * XBF);
    unsigned short* Hbf  = (unsigned short*)(w8 + 5 * XBF);
    unsigned short* wqbf = (unsigned short*)(w8 + 5 * XBF + HBF);
    unsigned short* wkbf = (unsigned short*)(w8 + 5 * XBF + HBF + WBLOB);
    unsigned short* wvbf = (unsigned short*)(w8 + 5 * XBF + HBF + 2 * WBLOB);
    unsigned short* wg1bf = (unsigned short*)(w8 + 5 * XBF + HBF + 3 * WBLOB);
    float* alpha = (float*)(w8 + 5 * XBF + HBF + 3 * WBLOB + (size_t)H_ * C_ * 2);

    const int xn4 = ROWS * C_ / 4;          // 2,560,000
    const int wn4 = 3 * C_ * C_ / 4;        // 49,152
    const int g1n4 = H_ * C_ / 4;           // 8,192

    // weight + x3 conversions
    cvt_kernel<<<(xn4 + 255) / 256, 256, 0, stream>>>(x3, x3bf, xn4);
    cvt_kernel<<<(wn4 + 255) / 256, 256, 0, stream>>>(Wq, wqbf, wn4);
    cvt_kernel<<<(wn4 + 255) / 256, 256, 0, stream>>>(Wk, wkbf, wn4);
    cvt_kernel<<<(wn4 + 255) / 256, 256, 0, stream>>>(Wv, wvbf, wn4);
    cvt_kernel<<<(g1n4 + 255) / 256, 256, 0, stream>>>(Wg1, wg1bf, g1n4);

    // gate: H = x3 @ Wg1^T + bg1 (MFMA), then softmax(relu(H)@Wg2^T+bg2)
    gemm_bf16<<<dim3(MT, 1, 1), 256, 0, stream>>>(
        x3bf, x3bf, wg1bf, wg1bf, wg1bf, bg1, bg1, bg1, Hbf, Hbf, Hbf, ROWS, H_);
    gate2_kernel<<<ROWS / 4, 256, 0, stream>>>(Hbf, Wg2, bg2, alpha);

    const float* xq[3] = {x0, x1, x2};
    for (int i = 0; i < 3; ++i) {
        cvt_kernel<<<(xn4 + 255) / 256, 256, 0, stream>>>(xq[i], xqbf, xn4);
        gemm_bf16<<<dim3(MT, 2, 3), 256, 0, stream>>>(
            xqbf, x3bf, wqbf + (size_t)i * C_ * C_, wkbf + (size_t)i * C_ * C_,
            wvbf + (size_t)i * C_ * C_, bq + i * C_, bk + i * C_, bv + i * C_,
            qbf, kbf, vbf, ROWS, C_);
        attn_kernel<<<ROWS / 4, 256, 0, stream>>>(qbf, kbf, vbf, knn, alpha,
                                                  ln_g, ln_b, out, i);
    }
    final_kernel<<<ROWS / 4, 256, 0, stream>>>(out, x3, fn_g, fn_b);
}

// Round 4
// 674.799 us; speedup vs baseline: 2.9718x; 1.0163x over previous
//
#include <hip/hip_runtime.h>

#define B_ 2
#define N_ 20000
#define C_ 256
#define K_ 16
#define H_ 128
#define ROWS (B_ * N_)       // 40000
#define MT 313               // ceil(40000/128)
#define MPAD (MT * 128)      // 40064

typedef __attribute__((ext_vector_type(8))) short bf16x8;
typedef __attribute__((ext_vector_type(4))) float f32x4;

__device__ __forceinline__ float us2f(unsigned short u) {
    return __uint_as_float(((unsigned int)u) << 16);
}
__device__ __forceinline__ unsigned short f2us(float f) {
    unsigned int u = __float_as_uint(f);
    unsigned int r = (u + 0x7fffu + ((u >> 16) & 1u)) >> 16;
    return (unsigned short)r;
}
__device__ __forceinline__ float wred(float v) {
#pragma unroll
    for (int off = 32; off > 0; off >>= 1) v += __shfl_xor(v, off, 64);
    return v;
}
__device__ __forceinline__ void gld_lds16(const unsigned short* g, unsigned short* l) {
    __builtin_amdgcn_global_load_lds(
        (__attribute__((address_space(1))) void*)(g),
        (__attribute__((address_space(3))) void*)(l), 16, 0, 0);
}

// ---------------- fp32 -> bf16 convert ---------------------------------------
extern "C" __global__ void __launch_bounds__(256)
cvt_kernel(const float* __restrict__ src, unsigned short* __restrict__ dst, int n4) {
    int t = blockIdx.x * 256 + threadIdx.x;
    if (t >= n4) return;
    float4 v = ((const float4*)src)[t];
    ushort4 o;
    o.x = f2us(v.x); o.y = f2us(v.y); o.z = f2us(v.z); o.w = f2us(v.w);
    ((ushort4*)dst)[t] = o;
}

// ---------------- batched weight convert (4 tensors, one dispatch) -----------
extern "C" __global__ void __launch_bounds__(256)
cvtw_kernel(const float* __restrict__ s0, const float* __restrict__ s1,
            const float* __restrict__ s2, const float* __restrict__ s3,
            unsigned short* __restrict__ d0, unsigned short* __restrict__ d1,
            unsigned short* __restrict__ d2, unsigned short* __restrict__ d3) {
    const int y = blockIdx.y;
    const float* src = (y == 0) ? s0 : (y == 1 ? s1 : (y == 2 ? s2 : s3));
    unsigned short* dst = (y == 0) ? d0 : (y == 1 ? d1 : (y == 2 ? d2 : d3));
    const int n4 = (y < 3) ? (3 * C_ * C_ / 4) : (H_ * C_ / 4);
    int t = blockIdx.x * 256 + threadIdx.x;
    if (t >= n4) return;
    float4 v = ((const float4*)src)[t];
    ushort4 o;
    o.x = f2us(v.x); o.y = f2us(v.y); o.z = f2us(v.z); o.w = f2us(v.w);
    ((ushort4*)dst)[t] = o;
}

// ---------------- bf16 MFMA GEMM: O = A @ W^T + b, O in bf16 -----------------
extern "C" __global__ void __launch_bounds__(256)
gemm_bf16(const unsigned short* __restrict__ A0, const unsigned short* __restrict__ A12,
          const unsigned short* __restrict__ W0, const unsigned short* __restrict__ W1,
          const unsigned short* __restrict__ W2, const float* __restrict__ b0,
          const float* __restrict__ b1, const float* __restrict__ b2,
          unsigned short* __restrict__ O0, unsigned short* __restrict__ O1,
          unsigned short* __restrict__ O2, const int Mvalid, const int ldo) {
    const int z = blockIdx.z;
    const unsigned short* A = (z == 0) ? A0 : A12;
    const unsigned short* W = (z == 0) ? W0 : (z == 1 ? W1 : W2);
    const float* bias = (z == 0) ? b0 : (z == 1 ? b1 : b2);
    unsigned short* O = (z == 0) ? O0 : (z == 1 ? O1 : O2);

    const int m0 = blockIdx.x * 128;
    const int n0 = blockIdx.y * 128;
    const int tid = threadIdx.x;
    const int w = tid >> 6, lane = tid & 63;
    const int l15 = lane & 15, l4 = lane >> 4;
    const int rowq = (w >> 1) * 64;   // wave quadrant
    const int colq = (w & 1) * 64;

    __shared__ unsigned short As[128 * 32];
    __shared__ unsigned short Bs[128 * 32];

    f32x4 acc[4][4] = {};

    const int srow = w * 16 + (lane >> 2);   // staging row within 64-row group
    const int schunk = (lane & 3) * 8;       // 8 bf16 = 16 B

    for (int k0 = 0; k0 < 256; k0 += 32) {
        __syncthreads();
#pragma unroll
        for (int issue = 0; issue < 2; ++issue) {
            const int ra = m0 + issue * 64 + srow;
            const int rb = n0 + issue * 64 + srow;
            gld_lds16(A + (size_t)ra * 256 + k0 + schunk, As + issue * 2048 + w * 512);
            gld_lds16(W + (size_t)rb * 256 + k0 + schunk, Bs + issue * 2048 + w * 512);
        }
        __syncthreads();
        bf16x8 a[4], b[4];
#pragma unroll
        for (int i = 0; i < 4; ++i)
            a[i] = *(const bf16x8*)&As[(rowq + i * 16 + l15) * 32 + l4 * 8];
#pragma unroll
        for (int j = 0; j < 4; ++j)
            b[j] = *(const bf16x8*)&Bs[(colq + j * 16 + l15) * 32 + l4 * 8];
#pragma unroll
        for (int i = 0; i < 4; ++i)
#pragma unroll
            for (int j = 0; j < 4; ++j)
                acc[i][j] = __builtin_amdgcn_mfma_f32_16x16x32_bf16(a[i], b[j], acc[i][j], 0, 0, 0);
    }

#pragma unroll
    for (int j = 0; j < 4; ++j) {
        const int gcol = n0 + colq + j * 16 + l15;
        const float bj = bias[gcol];
#pragma unroll
        for (int i = 0; i < 4; ++i) {
#pragma unroll
            for (int r = 0; r < 4; ++r) {
                const int grow = m0 + rowq + i * 16 + l4 * 4 + r;
                if (grow < Mvalid) O[(size_t)grow * ldo + gcol] = f2us(acc[i][j][r] + bj);
            }
        }
    }
}

// ---------------- gate stage 2: alpha = softmax(relu(H)@Wg2^T + bg2) ---------
extern "C" __global__ void __launch_bounds__(256)
gate2_kernel(const unsigned short* __restrict__ Hbf, const float* __restrict__ Wg2,
             const float* __restrict__ bg2, float* __restrict__ alpha) {
    const int tid = threadIdx.x;
    const int w = tid >> 6, lane = tid & 63;
    const int row = blockIdx.x * 4 + w;
    const float h0 = fmaxf(us2f(Hbf[(size_t)row * H_ + lane]), 0.f);
    const float h1 = fmaxf(us2f(Hbf[(size_t)row * H_ + 64 + lane]), 0.f);
    float lg[3];
#pragma unroll
    for (int l = 0; l < 3; ++l) {
        const float* w2 = Wg2 + l * H_;
        lg[l] = wred(h0 * w2[lane] + h1 * w2[lane + 64]) + bg2[l];
    }
    float m = fmaxf(lg[0], fmaxf(lg[1], lg[2]));
    float e0 = expf(lg[0] - m), e1 = expf(lg[1] - m), e2 = expf(lg[2] - m);
    float inv = 1.f / (e0 + e1 + e2);
    if (lane == 0) {
        alpha[row * 3 + 0] = e0 * inv;
        alpha[row * 3 + 1] = e1 * inv;
        alpha[row * 3 + 2] = e2 * inv;
    }
}

// ---------------- attention + LN + alpha-weighted accumulate into out --------
// 16 lanes per row, 4 rows per wave, 16 rows per block.
// lane t owns channels { j*64 + t*4 + [0,4) : j = 0..3 }.
extern "C" __global__ void __launch_bounds__(256)
attn_kernel(const unsigned short* __restrict__ q, const unsigned short* __restrict__ kf,
            const unsigned short* __restrict__ vf, const int* __restrict__ knn,
            const float* __restrict__ alpha, const float* __restrict__ lng,
            const float* __restrict__ lnb, float* __restrict__ accum, const int iblk) {
    const int tid = threadIdx.x;
    const int g = tid >> 4;          // row group [0,16)
    const int t = tid & 15;
    const int row = blockIdx.x * 16 + g;
    const int b = row / N_;
    const int n = row - b * N_;

    // ---- load Q (16 channels per lane, fp32 regs) ----
    float qv[16];
    const unsigned short* qp = q + (size_t)row * C_ + t * 4;
#pragma unroll
    for (int j = 0; j < 4; ++j) {
        ushort4 u = *(const ushort4*)(qp + j * 64);
        qv[j * 4 + 0] = us2f(u.x);
        qv[j * 4 + 1] = us2f(u.y);
        qv[j * 4 + 2] = us2f(u.z);
        qv[j * 4 + 3] = us2f(u.w);
    }

    // ---- pass 1: scores ----
    int idxs[K_];
    float s[K_];
#pragma unroll
    for (int k = 0; k < K_; ++k) {
        idxs[k] = knn[n * K_ + k];
        const unsigned short* kp = kf + ((size_t)b * N_ + idxs[k]) * C_ + t * 4;
        float p = 0.f;
#pragma unroll
        for (int j = 0; j < 4; ++j) {
            ushort4 u = *(const ushort4*)(kp + j * 64);
            p += qv[j * 4 + 0] * us2f(u.x) + qv[j * 4 + 1] * us2f(u.y) +
                 qv[j * 4 + 2] * us2f(u.z) + qv[j * 4 + 3] * us2f(u.w);
        }
#pragma unroll
        for (int off = 1; off < 16; off <<= 1) p += __shfl_xor(p, off, 64);
        s[k] = p * 0.0625f;
    }

    // ---- softmax over 16 (in-register, replicated across the 16 lanes) ----
    float m = s[0];
#pragma unroll
    for (int k = 1; k < K_; ++k) m = fmaxf(m, s[k]);
    float sum = 0.f;
#pragma unroll
    for (int k = 0; k < K_; ++k) {
        s[k] = __expf(s[k] - m);
        sum += s[k];
    }
    const float inv = 1.f / sum;

    // ---- pass 2: o = sum_k a_k * V[idx_k] ----
    float o[16] = {};
#pragma unroll
    for (int k = 0; k < K_; ++k) {
        const float a = s[k] * inv;
        const unsigned short* vp = vf + ((size_t)b * N_ + idxs[k]) * C_ + t * 4;
#pragma unroll
        for (int j = 0; j < 4; ++j) {
            ushort4 u = *(const ushort4*)(vp + j * 64);
            o[j * 4 + 0] += a * us2f(u.x);
            o[j * 4 + 1] += a * us2f(u.y);
            o[j * 4 + 2] += a * us2f(u.z);
            o[j * 4 + 3] += a * us2f(u.w);
        }
    }

    // ---- r = o + Q, LayerNorm over 256 ch (16 local + 4-stage group red) ----
    float r[16];
    float s1 = 0.f, s2 = 0.f;
#pragma unroll
    for (int c = 0; c < 16; ++c) {
        r[c] = o[c] + qv[c];
        s1 += r[c];
        s2 += r[c] * r[c];
    }
#pragma unroll
    for (int off = 1; off < 16; off <<= 1) {
        s1 += __shfl_xor(s1, off, 64);
        s2 += __shfl_xor(s2, off, 64);
    }
    const float mean = s1 * (1.f / C_);
    const float var = s2 * (1.f / C_) - mean * mean;
    const float rstd = rsqrtf(var + 1e-5f);

    const float a = alpha[row * 3 + iblk];
    const float* gp = lng + iblk * C_ + t * 4;
    const float* bp = lnb + iblk * C_ + t * 4;
    float* ap = accum + (size_t)row * C_ + t * 4;
#pragma unroll
    for (int j = 0; j < 4; ++j) {
        float4 gg = *(const float4*)(gp + j * 64);
        float4 bb = *(const float4*)(bp + j * 64);
        float4 y;
        y.x = ((r[j * 4 + 0] - mean) * rstd * gg.x + bb.x) * a;
        y.y = ((r[j * 4 + 1] - mean) * rstd * gg.y + bb.y) * a;
        y.z = ((r[j * 4 + 2] - mean) * rstd * gg.z + bb.z) * a;
        y.w = ((r[j * 4 + 3] - mean) * rstd * gg.w + bb.w) * a;
        if (iblk == 0) {
            *(float4*)(ap + j * 64) = y;
        } else {
            float4 p = *(const float4*)(ap + j * 64);
            p.x += y.x; p.y += y.y; p.z += y.z; p.w += y.w;
            *(float4*)(ap + j * 64) = p;
        }
    }
}

// ---------------- final LN(accum + x3), in-place on out ----------------------
extern "C" __global__ void __launch_bounds__(256)
final_kernel(float* __restrict__ accum, const float* __restrict__ x3,
             const float* __restrict__ fng, const float* __restrict__ fnb) {
    const int tid = threadIdx.x;
    const int w = tid >> 6, lane = tid & 63;
    const int row = blockIdx.x * 4 + w;
    const int c0 = lane * 4;
    float4 a = *(const float4*)(accum + (size_t)row * C_ + c0);
    float4 xv = *(const float4*)(x3 + (size_t)row * C_ + c0);
    float4 r = make_float4(a.x + xv.x, a.y + xv.y, a.z + xv.z, a.w + xv.w);
    float s1 = wred(r.x + r.y + r.z + r.w);
    float s2 = wred(r.x * r.x + r.y * r.y + r.z * r.z + r.w * r.w);
    const float mean = s1 * (1.f / C_);
    const float var = s2 * (1.f / C_) - mean * mean;
    const float rstd = rsqrtf(var + 1e-5f);
    const float* g = fng + c0;
    const float* bb = fnb + c0;
    float4 y;
    y.x = (r.x - mean) * rstd * g[0] + bb[0];
    y.y = (r.y - mean) * rstd * g[1] + bb[1];
    y.z = (r.z - mean) * rstd * g[2] + bb[2];
    y.w = (r.w - mean) * rstd * g[3] + bb[3];
    *(float4*)(accum + (size_t)row * C_ + c0) = y;
}

extern "C" void kernel_launch(void* const* d_in, const int* in_sizes, int n_in,
                              void* d_out, int out_size, void* d_ws, size_t ws_size,
                              hipStream_t stream) {
    const float* x0 = (const float*)d_in[0];
    const float* x1 = (const float*)d_in[1];
    const float* x2 = (const float*)d_in[2];
    const float* x3 = (const float*)d_in[3];
    const int* knn = (const int*)d_in[4];
    const float* Wq = (const float*)d_in[5];
    const float* bq = (const float*)d_in[6];
    const float* Wk = (const float*)d_in[7];
    const float* bk = (const float*)d_in[8];
    const float* Wv = (const float*)d_in[9];
    const float* bv = (const float*)d_in[10];
    const float* ln_g = (const float*)d_in[11];
    const float* ln_b = (const float*)d_in[12];
    const float* Wg1 = (const float*)d_in[13];
    const float* bg1 = (const float*)d_in[14];
    const float* Wg2 = (const float*)d_in[15];
    const float* bg2 = (const float*)d_in[16];
    const float* fn_g = (const float*)d_in[17];
    const float* fn_b = (const float*)d_in[18];
    float* out = (float*)d_out;

    unsigned char* w8 = (unsigned char*)d_ws;
    const size_t XBF = (size_t)MPAD * C_ * 2;        // 20,512,768 B
    const size_t HBF = (size_t)MPAD * H_ * 2;        // 10,256,384 B
    const size_t WBLOB = (size_t)3 * C_ * C_ * 2;    //    393,216 B
    unsigned short* x3bf = (unsigned short*)(w8);
    unsigned short* xqbf = (unsigned short*)(w8 + XBF);
    unsigned short* qbf  = (unsigned short*)(w8 + 2 * XBF);
    unsigned short* kbf  = (unsigned short*)(w8 + 3 * XBF);
    unsigned short* vbf  = (unsigned short*)(w8 + 4 * XBF);
    unsigned short* Hbf  = (unsigned short*)(w8 + 5 * XBF);
    unsigned short* wqbf = (unsigned short*)(w8 + 5 * XBF + HBF);
    unsigned short* wkbf = (unsigned short*)(w8 + 5 * XBF + HBF + WBLOB);
    unsigned short* wvbf = (unsigned short*)(w8 + 5 * XBF + HBF + 2 * WBLOB);
    unsigned short* wg1bf = (unsigned short*)(w8 + 5 * XBF + HBF + 3 * WBLOB);
    float* alpha = (float*)(w8 + 5 * XBF + HBF + 3 * WBLOB + (size_t)H_ * C_ * 2);

    const int xn4 = ROWS * C_ / 4;          // 2,560,000
    const int wn4 = 3 * C_ * C_ / 4;        // 49,152

    // conversions: x3 + all weights
    cvt_kernel<<<(xn4 + 255) / 256, 256, 0, stream>>>(x3, x3bf, xn4);
    cvtw_kernel<<<dim3((wn4 + 255) / 256, 4), 256, 0, stream>>>(
        Wq, Wk, Wv, Wg1, wqbf, wkbf, wvbf, wg1bf);

    // gate: H = x3 @ Wg1^T + bg1 (MFMA), then softmax(relu(H)@Wg2^T+bg2)
    gemm_bf16<<<dim3(MT, 1, 1), 256, 0, stream>>>(
        x3bf, x3bf, wg1bf, wg1bf, wg1bf, bg1, bg1, bg1, Hbf, Hbf, Hbf, ROWS, H_);
    gate2_kernel<<<ROWS / 4, 256, 0, stream>>>(Hbf, Wg2, bg2, alpha);

    const float* xq[3] = {x0, x1, x2};
    for (int i = 0; i < 3; ++i) {
        cvt_kernel<<<(xn4 + 255) / 256, 256, 0, stream>>>(xq[i], xqbf, xn4);
        gemm_bf16<<<dim3(MT, 2, 3), 256, 0, stream>>>(
            xqbf, x3bf, wqbf + (size_t)i * C_ * C_, wkbf + (size_t)i * C_ * C_,
            wvbf + (size_t)i * C_ * C_, bq + i * C_, bk + i * C_, bv + i * C_,
            qbf, kbf, vbf, ROWS, C_);
        attn_kernel<<<ROWS / 16, 256, 0, stream>>>(qbf, kbf, vbf, knn, alpha,
                                                   ln_g, ln_b, out, i);
    }
    final_kernel<<<ROWS / 4, 256, 0, stream>>>(out, x3, fn_g, fn_b);
}